// Round 1
// baseline (898.745 us; speedup 1.0000x reference)
//
#include <hip/hip_runtime.h>
#include <hip/hip_bf16.h>

#define N_TOTAL  500000
#define NUM_NODE 100000
#define IN_DIM   256
#define HID      256
#define K_TOT    512
#define BM       128
#define BN       128
#define BK       32

typedef __bf16 bf16x8 __attribute__((ext_vector_type(8)));
typedef float  f32x4  __attribute__((ext_vector_type(4)));

__device__ __forceinline__ ushort f2bf(float f) {
  unsigned u = __builtin_bit_cast(unsigned, f);
  u = (u + 0x7fffu + ((u >> 16) & 1u)) >> 16;   // round-to-nearest-even
  return (ushort)u;
}

// One wave (64 lanes) per node. Each lane owns 4 contiguous floats (float4)
// of the 256-dim feature row. Hit nodes copy the history row; miss nodes
// compute the mean of neighbor rows (coalesced 1KB row gathers).
__global__ __launch_bounds__(256) void agg_his_kernel(
    const float* __restrict__ x, const int* __restrict__ ptr,
    const int* __restrict__ idx, const int* __restrict__ hmap,
    const float* __restrict__ hbuf, float* __restrict__ his)
{
  int wid  = blockIdx.x * 4 + (threadIdx.x >> 6);
  if (wid >= NUM_NODE) return;
  int lane = threadIdx.x & 63;
  const float4* xv = reinterpret_cast<const float4*>(x);

  int hm = hmap[wid];              // wave-uniform -> uniform branch
  float4 v;
  if (hm >= 0) {
    v = reinterpret_cast<const float4*>(hbuf)[(size_t)hm * 64 + lane];
  } else {
    int e0 = ptr[wid], e1 = ptr[wid + 1];
    float ax = 0.f, ay = 0.f, az = 0.f, aw = 0.f;
    int e = e0;
    for (; e + 4 <= e1; e += 4) {   // 4-wide idx prefetch for MLP
      int j0 = idx[e], j1 = idx[e + 1], j2 = idx[e + 2], j3 = idx[e + 3];
      float4 t0 = xv[(size_t)j0 * 64 + lane];
      float4 t1 = xv[(size_t)j1 * 64 + lane];
      float4 t2 = xv[(size_t)j2 * 64 + lane];
      float4 t3 = xv[(size_t)j3 * 64 + lane];
      ax += t0.x; ay += t0.y; az += t0.z; aw += t0.w;
      ax += t1.x; ay += t1.y; az += t1.z; aw += t1.w;
      ax += t2.x; ay += t2.y; az += t2.z; aw += t2.w;
      ax += t3.x; ay += t3.y; az += t3.z; aw += t3.w;
    }
    for (; e < e1; ++e) {
      int j = idx[e];
      float4 t = xv[(size_t)j * 64 + lane];
      ax += t.x; ay += t.y; az += t.z; aw += t.w;
    }
    float inv = 1.0f / fmaxf((float)(e1 - e0), 1.0f);
    v.x = ax * inv; v.y = ay * inv; v.z = az * inv; v.w = aw * inv;
  }
  reinterpret_cast<float4*>(his)[(size_t)wid * 64 + lane] = v;
}

// Fused dual GEMM: out[m][n] = sum_k [his|x](m,k) * [Wl|Wr](n,k) + bl[n].
// A = [his | x_targets]  (M=100000, K=512), row-major fp32, converted to bf16
// B^T = [Wl | Wr]        (N=256,    K=512), row-major fp32 (native layout!)
// 128x128 tile, 4 waves (2x2), each wave 64x64 = 4x4 of 16x16x32 MFMA tiles.
__global__ __launch_bounds__(256) void fused_gemm_kernel(
    const float* __restrict__ his, const float* __restrict__ x,
    const float* __restrict__ Wl, const float* __restrict__ Wr,
    const float* __restrict__ bl, float* __restrict__ out)
{
  __shared__ ushort As[BM][BK + 8];   // +8 ushort = 16B pad vs bank conflicts
  __shared__ ushort Bs[BN][BK + 8];

  const int t    = threadIdx.x;
  const int lane = t & 63;
  const int w    = t >> 6;
  const int wr   = w >> 1, wc = w & 1;
  const int bm0  = blockIdx.x * BM;
  const int bn0  = blockIdx.y * BN;

  f32x4 acc[4][4] = {};

  for (int kt = 0; kt < K_TOT / BK; ++kt) {
    __syncthreads();
    // Stage A and B tiles: 128x32 fp32 each -> bf16 LDS. 4 iters x 256 thr x float4.
    #pragma unroll
    for (int i = 0; i < 4; ++i) {
      int li  = i * 256 + t;       // 0..1023
      int row = li >> 3;           // 0..127
      int seg = li & 7;            // 0..7  (4 floats each)
      int kg  = kt * BK + seg * 4; // global k

      int gm = bm0 + row; if (gm >= NUM_NODE) gm = NUM_NODE - 1;
      const float* srcA = (kg < IN_DIM)
          ? (his + (size_t)gm * IN_DIM + kg)
          : (x   + (size_t)gm * IN_DIM + (kg - IN_DIM));
      float4 a = *reinterpret_cast<const float4*>(srcA);
      ushort4 ua; ua.x = f2bf(a.x); ua.y = f2bf(a.y); ua.z = f2bf(a.z); ua.w = f2bf(a.w);
      *reinterpret_cast<ushort4*>(&As[row][seg * 4]) = ua;

      int gn = bn0 + row;          // always < 256
      const float* srcB = (kg < IN_DIM)
          ? (Wl + (size_t)gn * IN_DIM + kg)
          : (Wr + (size_t)gn * IN_DIM + (kg - IN_DIM));
      float4 b = *reinterpret_cast<const float4*>(srcB);
      ushort4 ub; ub.x = f2bf(b.x); ub.y = f2bf(b.y); ub.z = f2bf(b.z); ub.w = f2bf(b.w);
      *reinterpret_cast<ushort4*>(&Bs[row][seg * 4]) = ub;
    }
    __syncthreads();

    // A frag: row = lane&15, k = (lane>>4)*8 + j (8 contiguous bf16 = b128)
    bf16x8 af[4], bfr[4];
    #pragma unroll
    for (int mi = 0; mi < 4; ++mi)
      af[mi] = *reinterpret_cast<const bf16x8*>(
          &As[wr * 64 + mi * 16 + (lane & 15)][(lane >> 4) * 8]);
    #pragma unroll
    for (int ni = 0; ni < 4; ++ni)
      bfr[ni] = *reinterpret_cast<const bf16x8*>(
          &Bs[wc * 64 + ni * 16 + (lane & 15)][(lane >> 4) * 8]);

    #pragma unroll
    for (int mi = 0; mi < 4; ++mi)
      #pragma unroll
      for (int ni = 0; ni < 4; ++ni)
        acc[mi][ni] = __builtin_amdgcn_mfma_f32_16x16x32_bf16(
            af[mi], bfr[ni], acc[mi][ni], 0, 0, 0);
  }

  // Epilogue: C/D layout col=lane&15, row=(lane>>4)*4+j (verified m89/m91)
  #pragma unroll
  for (int mi = 0; mi < 4; ++mi) {
    #pragma unroll
    for (int ni = 0; ni < 4; ++ni) {
      int r0 = bm0 + wr * 64 + mi * 16 + (lane >> 4) * 4;
      int c  = bn0 + wc * 64 + ni * 16 + (lane & 15);
      float bias = bl[c];
      #pragma unroll
      for (int j = 0; j < 4; ++j) {
        int r = r0 + j;
        if (r < NUM_NODE) out[(size_t)r * HID + c] = acc[mi][ni][j] + bias;
      }
    }
  }
}

extern "C" void kernel_launch(void* const* d_in, const int* in_sizes, int n_in,
                              void* d_out, int out_size, void* d_ws, size_t ws_size,
                              hipStream_t stream) {
  const float* x    = (const float*)d_in[0];
  const int*   ptr  = (const int*)d_in[1];
  const int*   idx  = (const int*)d_in[2];
  const int*   hmap = (const int*)d_in[3];
  const float* hbuf = (const float*)d_in[4];
  // d_in[5] = history_size (20000), d_in[6] = num_node (100000): constants
  const float* Wl   = (const float*)d_in[7];
  const float* bl   = (const float*)d_in[8];
  const float* Wr   = (const float*)d_in[9];

  float* out = (float*)d_out;                          // [NUM_NODE, HID]
  float* his = out + (size_t)NUM_NODE * HID;           // [NUM_NODE, IN_DIM]

  agg_his_kernel<<<dim3((NUM_NODE + 3) / 4), 256, 0, stream>>>(
      x, ptr, idx, hmap, hbuf, his);

  dim3 grid((NUM_NODE + BM - 1) / BM, HID / BN);
  fused_gemm_kernel<<<grid, 256, 0, stream>>>(his, x, Wl, Wr, bl, out);
}